// Round 1
// baseline (226.924 us; speedup 1.0000x reference)
//
#include <hip/hip_runtime.h>

#define THRESH 0.7f

__global__ __launch_bounds__(256) void rnet_post_kernel(
    const float2* __restrict__ cls,    // [M] pairs: (bg, face) score
    const float4* __restrict__ reg,    // [M] dx1,dy1,dx2,dy2
    const float4* __restrict__ rects,  // [M] x1,y1,x2,y2
    const int*    __restrict__ hptr,   // input_height (1 elem)
    const int*    __restrict__ wptr,   // input_width  (1 elem)
    float4* __restrict__ out_rects,    // [M]
    float*  __restrict__ out_scores,   // [M]
    float*  __restrict__ out_keep,     // [M]
    int M)
{
    int i = blockIdx.x * blockDim.x + threadIdx.x;
    if (i >= M) return;

    const float fh = (float)*hptr;
    const float fw = (float)*wptr;

    float2 c = cls[i];
    float score = c.y;
    float keep = (score > THRESH) ? 1.0f : 0.0f;

    float4 r = rects[i];
    float4 d = reg[i];
    float w = r.z - r.x;
    float h = r.w - r.y;

    float nx1 = fminf(fmaxf(fmaf(d.x, w, r.x), 0.0f), fw);
    float ny1 = fminf(fmaxf(fmaf(d.y, h, r.y), 0.0f), fh);
    float nx2 = fminf(fmaxf(fmaf(d.z, w, r.z), 0.0f), fw);
    float ny2 = fminf(fmaxf(fmaf(d.w, h, r.w), 0.0f), fh);

    out_rects[i]  = make_float4(nx1 * keep, ny1 * keep, nx2 * keep, ny2 * keep);
    out_scores[i] = score * keep;
    out_keep[i]   = keep;
}

extern "C" void kernel_launch(void* const* d_in, const int* in_sizes, int n_in,
                              void* d_out, int out_size, void* d_ws, size_t ws_size,
                              hipStream_t stream) {
    const float2* cls   = (const float2*)d_in[0];  // classifier [B,N,2]
    const float4* reg   = (const float4*)d_in[1];  // bbox_regress [B,N,4]
    const float4* rects = (const float4*)d_in[2];  // input_rects [B,N,4]
    const int*    hptr  = (const int*)d_in[3];     // input_height scalar
    const int*    wptr  = (const int*)d_in[4];     // input_width scalar

    const int M = in_sizes[0] / 2;  // B*N

    float* out = (float*)d_out;
    float4* out_rects  = (float4*)out;        // 4*M floats
    float*  out_scores = out + 4ll * M;       // M floats
    float*  out_keep   = out + 5ll * M;       // M floats

    const int block = 256;
    const int grid = (M + block - 1) / block;
    rnet_post_kernel<<<grid, block, 0, stream>>>(cls, reg, rects, hptr, wptr,
                                                 out_rects, out_scores, out_keep, M);
}